// Round 2
// 302.094 us; speedup vs baseline: 1.0715x; 1.0715x over previous
//
#include <hip/hip_runtime.h>
#include <cstdint>

#define M_PTS 8192
#define N_QRY 8192
#define BATCH 4

// ---------------- helpers ----------------
__device__ __forceinline__ float d2_exact(float qx, float qy, float qz, float q2, float4 p) {
#pragma clang fp contract(off)
  float dot = (qx * p.x + qy * p.y) + qz * p.z;   // reference op order, no fma
  return (q2 + p.w) - 2.0f * dot;
}

__device__ __forceinline__ unsigned flipf(float d) {
  unsigned u = __float_as_uint(d);
  return u ^ ((unsigned)((int)u >> 31) | 0x80000000u);   // order-preserving float->uint
}

__device__ __forceinline__ int lane_prefix(unsigned long long m) {
  return __builtin_amdgcn_mbcnt_hi((unsigned)(m >> 32),
         __builtin_amdgcn_mbcnt_lo((unsigned)m, 0));
}

__device__ __forceinline__ void ld_lds16(const float4* g, float4* l) {
  __builtin_amdgcn_global_load_lds((const __attribute__((address_space(1))) void*)g,
                                   (__attribute__((address_space(3))) void*)l, 16, 0, 0);
}

// Upper bound on the 16th-smallest of the 64 per-lane mins, via ballot bisection.
// Invariant: count(hi) >= 16 (init hi = wave max -> count = 64). 12 steps give
// resolution (hi0-lo0)/4096 << the 0.01 collection margin. Returned hi >= the
// 16th smallest lane-min >= the chunk's 16th smallest value -> no true top-16
// point is ever excluded.
__device__ __forceinline__ float tau16(float mn) {
  float lo = mn, hi = mn;
#pragma unroll
  for (int j = 1; j < 64; j <<= 1) {
    lo = fminf(lo, __shfl_xor(lo, j));
    hi = fmaxf(hi, __shfl_xor(hi, j));
  }
#pragma unroll
  for (int it = 0; it < 12; it++) {
    float mid = 0.5f * (lo + hi);
    int cnt = __popcll(__ballot(mn <= mid));
    if (cnt >= 16) hi = mid; else lo = mid;   // wave-uniform
  }
  return hi;
}

// ---------------- K0a: pack (x, y, z, x^2+y^2+z^2) ----------------
__global__ void pack_pts(const float* __restrict__ src, float4* __restrict__ dst, int total) {
#pragma clang fp contract(off)
  int i = blockIdx.x * 256 + threadIdx.x;
  if (i >= total) return;
  int b = i >> 13, m = i & (M_PTS - 1);
  const float* s = src + (size_t)b * 3 * M_PTS;
  float x = s[m], y = s[M_PTS + m], z = s[2 * M_PTS + m];
  float ss = (x * x + y * y) + z * z;   // matches jnp.sum(pts**2, axis=1) order
  dst[i] = make_float4(x, y, z, ss);
}

// ---------------- K0b: transpose local_feat (B,64,M) -> (B,M,64) ----------------
__global__ void transpose_lf(const float* __restrict__ lf, float* __restrict__ lfT) {
  __shared__ float tile[64][65];
  int bb = blockIdx.x >> 7;
  int m0 = (blockIdx.x & 127) << 6;
  int tm = threadIdx.x & 63;
  int tc = threadIdx.x >> 6;
  const float* src = lf + (size_t)bb * 64 * M_PTS;
#pragma unroll
  for (int i = 0; i < 16; i++) {
    int ch = i * 4 + tc;
    tile[ch][tm] = src[(size_t)ch * M_PTS + m0 + tm];
  }
  __syncthreads();
  float* dst = lfT + ((size_t)bb * M_PTS + m0) * 64;
#pragma unroll
  for (int i = 0; i < 16; i++) {
    int mm = i * 4 + tc;
    dst[(size_t)mm * 64 + tm] = tile[tm][mm];
  }
}

// ---------------- K1: exact KNN top-16, 2 queries per wave ----------------
// Restructured (R1): 4 chunks of 2048 points, per-chunk tau. Only 64 e-values
// (32 per query) are live at any point -> no register spill, and LDS of 38.9 KB
// allows 4 blocks/CU (__launch_bounds__(256,4), 50% occupancy target).
// Per-chunk tau correctness: a global top-16 point in chunk c has chunk-rank
// <= 16; tau_c >= 16th-smallest lane-min >= chunk 16th-smallest value, +0.01
// margin covers fma-vs-exact divergence. Candidates re-scored with the exact
// reference d2 tree before final selection -> bit-identical ordering.
__global__ void __launch_bounds__(256, 4) knn_kernel(const float4* __restrict__ pp,
                                                     const float4* __restrict__ qp,
                                                     int* __restrict__ knn_out) {
  __shared__ float4 spts[2048];          // 32 KB staged point chunk
  __shared__ unsigned cand[8][192];      // 6 KB candidate index buffers (per wave x 2 q)
  const int tid = threadIdx.x;
  const int lane = tid & 63;
  const int wave = tid >> 6;
  const int b = blockIdx.x >> 10;                 // 1024 blocks per batch
  const int qa = blockIdx.x * 8 + wave * 2;       // this wave's two queries
  const float4* pb = pp + ((size_t)b << 13);

  const float4 A4 = qp[qa];
  const float4 B4 = qp[qa + 1];
  const float axA = -2.0f * A4.x, ayA = -2.0f * A4.y, azA = -2.0f * A4.z;
  const float axB = -2.0f * B4.x, ayB = -2.0f * B4.y, azB = -2.0f * B4.z;

  int cntA = 0, cntB = 0;
  unsigned* cqA = cand[wave * 2 + 0];
  unsigned* cqB = cand[wave * 2 + 1];

  for (int c = 0; c < 4; ++c) {
    __syncthreads();                      // protect spts from previous chunk's readers
#pragma unroll
    for (int i = 0; i < 8; i++) {
      const float4* g = pb + c * 2048 + i * 256 + wave * 64 + lane;
      ld_lds16(g, &spts[i * 256 + wave * 64]);   // wave-uniform LDS base + lane*16
    }
    __syncthreads();                      // drains vmcnt -> data visible

    float eA[32], eB[32];
    float mnA = 3.402823466e38f, mnB = 3.402823466e38f;
#pragma unroll
    for (int j = 0; j < 32; j++) {
      float4 p = spts[j * 64 + lane];
      float ea = __builtin_fmaf(axA, p.x, __builtin_fmaf(ayA, p.y,
                 __builtin_fmaf(azA, p.z, p.w)));
      float eb = __builtin_fmaf(axB, p.x, __builtin_fmaf(ayB, p.y,
                 __builtin_fmaf(azB, p.z, p.w)));
      eA[j] = ea;
      eB[j] = eb;
      mnA = fminf(mnA, ea);
      mnB = fminf(mnB, eb);
    }
    float tauA = tau16(mnA) + 0.01f;      // margin >> fma-vs-exact divergence
    float tauB = tau16(mnB) + 0.01f;

#pragma unroll
    for (int j = 0; j < 32; j++) {
      unsigned idx = (unsigned)(c * 2048 + j * 64 + lane);
      {
        bool pred = eA[j] <= tauA;
        unsigned long long mask = __ballot(pred);
        if (mask) {                        // wave-uniform branch
          int pos = cntA + lane_prefix(mask);
          if (pred && pos < 192) cqA[pos] = idx;
          cntA += __popcll(mask);
        }
      }
      {
        bool pred = eB[j] <= tauB;
        unsigned long long mask = __ballot(pred);
        if (mask) {
          int pos = cntB + lane_prefix(mask);
          if (pred && pos < 192) cqB[pos] = idx;
          cntB += __popcll(mask);
        }
      }
    }
  }

  auto finalize = [&](const unsigned* cq, int cnt, int gq,
                      float qx, float qy, float qz, float q2) {
    int E = cnt < 192 ? cnt : 192;            // E >= 64 guaranteed (>=16 per chunk)
    unsigned i0 = (lane < E) ? cq[lane] : 0u;
    unsigned i1 = (lane + 64 < E) ? cq[lane + 64] : 0u;
    unsigned i2 = (lane + 128 < E) ? cq[lane + 128] : 0u;
    float4 p0 = pb[i0];                       // parallel L2-hit loads
    float4 p1 = pb[i1];
    float4 p2 = pb[i2];
    unsigned long long k0 = ~0ull, k1 = ~0ull, k2 = ~0ull;
    if (lane < E)
      k0 = ((unsigned long long)flipf(d2_exact(qx, qy, qz, q2, p0)) << 32) | i0;
    if (lane + 64 < E)
      k1 = ((unsigned long long)flipf(d2_exact(qx, qy, qz, q2, p1)) << 32) | i1;
    if (lane + 128 < E)
      k2 = ((unsigned long long)flipf(d2_exact(qx, qy, qz, q2, p2)) << 32) | i2;
    unsigned my = 0;
#pragma unroll
    for (int t = 0; t < 16; t++) {
      unsigned long long m = k0 < k1 ? k0 : k1;
      if (k2 < m) m = k2;
#pragma unroll
      for (int j = 1; j < 64; j <<= 1) {
        unsigned long long o = __shfl_xor(m, j);
        if (o < m) m = o;
      }
      if (lane == t) my = (unsigned)m;
      if (k0 == m) k0 = ~0ull;
      else if (k1 == m) k1 = ~0ull;
      else if (k2 == m) k2 = ~0ull;
    }
    if (lane < 16) knn_out[(size_t)gq * 16 + lane] = (int)my;
  };

  finalize(cqA, cntA, qa,     A4.x, A4.y, A4.z, A4.w);
  finalize(cqB, cntB, qa + 1, B4.x, B4.y, B4.z, B4.w);
}

// ---------------- K2: fused feature pipeline, 16 queries per block ----------------
// lane = channel. w1 row lives in 64 VGPRs per lane (raw weights; BN scale applied
// after accumulation). relbuf/f0v are wave-local: lockstep wave => no barrier needed.
__global__ void __launch_bounds__(256, 3) feat_kernel(
    const float4* __restrict__ pp, const float4* __restrict__ qp,
    const int* __restrict__ knn, const float* __restrict__ lfT,
    const float* __restrict__ w0, const float* __restrict__ b0,
    const float* __restrict__ g0, const float* __restrict__ be0,
    const float* __restrict__ m0, const float* __restrict__ v0,
    const float* __restrict__ w1, const float* __restrict__ b1,
    const float* __restrict__ g1, const float* __restrict__ be1,
    const float* __restrict__ m1, const float* __restrict__ v1,
    const float* __restrict__ w2, const float* __restrict__ b2,
    float* __restrict__ out) {
  __shared__ float4 relbuf[4][16];
  __shared__ float4 f0v[4][64];
  __shared__ float outbuf[64][17];     // +1 pad breaks write-phase bank conflicts
  const int tid = threadIdx.x;
  const int lane = tid & 63;
  const int wave = tid >> 6;
  const int gq0 = blockIdx.x * 16;
  const int b = gq0 >> 13;

  // BN folds (inline; fp order matches R0's fold_kernel)
  const float inv0 = g0[lane] / sqrtf(v0[lane] + 1e-5f);
  const float w00 = w0[lane * 3 + 0] * inv0;
  const float w01 = w0[lane * 3 + 1] * inv0;
  const float w02 = w0[lane * 3 + 2] * inv0;
  const float bb0 = (b0[lane] - m0[lane]) * inv0 + be0[lane];
  const float inv1 = g1[lane] / sqrtf(v1[lane] + 1e-5f);
  const float bb1 = (b1[lane] - m1[lane]) * inv1 + be1[lane];

  float w1s[64];
#pragma unroll
  for (int i = 0; i < 16; i++) {
    float4 t = ((const float4*)(w1 + (size_t)lane * 64))[i];
    w1s[i * 4 + 0] = t.x; w1s[i * 4 + 1] = t.y;
    w1s[i * 4 + 2] = t.z; w1s[i * 4 + 3] = t.w;
  }
  const float w2a = w2[lane], w2b = w2[64 + lane];
  const float bias2 = b2[0];
  const float4* pb = pp + ((size_t)b << 13);
  const float* lfb = lfT + (((size_t)b << 13)) * 64;

  for (int qi = 0; qi < 4; qi++) {
    const int gq = gq0 + wave * 4 + qi;
    const float4 q4 = qp[gq];
    int nk = knn[(size_t)gq * 16 + (lane & 15)];
    float4 pk = pb[nk];
    if (lane < 16)
      relbuf[wave][lane] = make_float4(pk.x - q4.x, pk.y - q4.y, pk.z - q4.z, 0.0f);
    // wave-local RAW: lgkmcnt ordering suffices, no barrier

    float g = 0.0f, f0 = 0, f1 = 0, f2 = 0, f3 = 0;
#pragma unroll
    for (int k = 0; k < 16; k++) {
      float4 r = relbuf[wave][k];
      float y = fmaxf(0.0f, w00 * r.x + w01 * r.y + w02 * r.z + bb0);
      g = fmaxf(g, y);
      if (k == 0) f0 = y; else if (k == 1) f1 = y;
      else if (k == 2) f2 = y; else if (k == 3) f3 = y;
    }
    f0v[wave][lane] = make_float4(f0, f1, f2, f3);

    float a0 = 0, a1 = 0, a2 = 0, a3 = 0;
#pragma unroll
    for (int c2 = 0; c2 < 64; c2++) {
      float w = w1s[c2];                 // register (compile-time index)
      float4 fb = f0v[wave][c2];         // LDS broadcast
      a0 = fmaf(w, fb.x, a0); a1 = fmaf(w, fb.y, a1);
      a2 = fmaf(w, fb.z, a2); a3 = fmaf(w, fb.w, a3);
    }
    float r0 = fmaxf(0.0f, fmaf(a0, inv1, bb1));
    float r1 = fmaxf(0.0f, fmaf(a1, inv1, bb1));
    float r2 = fmaxf(0.0f, fmaf(a2, inv1, bb1));
    float r3 = fmaxf(0.0f, fmaf(a3, inv1, bb1));

    int i0 = __shfl(nk, 0), i1 = __shfl(nk, 1), i2 = __shfl(nk, 2), i3 = __shfl(nk, 3);
    float p0 = lfb[(size_t)i0 * 64 + lane];
    float p1 = lfb[(size_t)i1 * 64 + lane];
    float p2 = lfb[(size_t)i2 * 64 + lane];
    float p3 = lfb[(size_t)i3 * 64 + lane];

    float s0 = w2a * r0, s1 = w2a * r1, s2 = w2a * r2, s3 = w2a * r3, tg = w2b * g;
#pragma unroll
    for (int j = 1; j < 64; j <<= 1) {
      s0 += __shfl_xor(s0, j);
      s1 += __shfl_xor(s1, j);
      s2 += __shfl_xor(s2, j);
      s3 += __shfl_xor(s3, j);
      tg += __shfl_xor(tg, j);
    }
    float wk0 = 1.0f / (1.0f + __expf(-(s0 + tg + bias2)));
    float wk1 = 1.0f / (1.0f + __expf(-(s1 + tg + bias2)));
    float wk2 = 1.0f / (1.0f + __expf(-(s2 + tg + bias2)));
    float wk3 = 1.0f / (1.0f + __expf(-(s3 + tg + bias2)));

    float oc = ((1.0f - wk0) * r0 + wk0 * p0)
             + ((1.0f - wk1) * r1 + wk1 * p1)
             + ((1.0f - wk2) * r2 + wk2 * p2)
             + ((1.0f - wk3) * r3 + wk3 * p3);
    outbuf[lane][wave * 4 + qi] = oc;
  }
  __syncthreads();

  // coalesced output: thread t -> channel c = t>>2, 4 queries via float4
  int c = tid >> 2, j = tid & 3;
  float4 o4 = make_float4(outbuf[c][j * 4 + 0], outbuf[c][j * 4 + 1],
                          outbuf[c][j * 4 + 2], outbuf[c][j * 4 + 3]);
  *(float4*)(out + (((size_t)(b * 64 + c)) << 13) + (gq0 & (N_QRY - 1)) + j * 4) = o4;
}

extern "C" void kernel_launch(void* const* d_in, const int* in_sizes, int n_in,
                              void* d_out, int out_size, void* d_ws, size_t ws_size,
                              hipStream_t stream) {
  (void)in_sizes; (void)n_in; (void)out_size; (void)ws_size;
  const float* original_pts = (const float*)d_in[0];
  const float* query_pts   = (const float*)d_in[1];
  const float* local_feat  = (const float*)d_in[2];
  const float* w0 = (const float*)d_in[3];
  const float* b0 = (const float*)d_in[4];
  const float* g0 = (const float*)d_in[5];
  const float* be0 = (const float*)d_in[6];
  const float* m0 = (const float*)d_in[7];
  const float* v0 = (const float*)d_in[8];
  const float* w1 = (const float*)d_in[9];
  const float* b1 = (const float*)d_in[10];
  const float* g1 = (const float*)d_in[11];
  const float* be1 = (const float*)d_in[12];
  const float* m1 = (const float*)d_in[13];
  const float* v1 = (const float*)d_in[14];
  const float* w2 = (const float*)d_in[15];
  const float* b2 = (const float*)d_in[16];
  float* out = (float*)d_out;

  // workspace layout (16B aligned), total ~11.5 MB
  char* ws = (char*)d_ws;
  float4* pp  = (float4*)(ws);                 // 512 KB
  float4* qp  = (float4*)(ws + 524288);        // 512 KB
  float*  lfT = (float*)(ws + 1048576);        // 8 MB
  int*    knn = (int*)(ws + 9437184);          // 2 MB

  pack_pts<<<128, 256, 0, stream>>>(original_pts, pp, BATCH * M_PTS);
  pack_pts<<<128, 256, 0, stream>>>(query_pts, qp, BATCH * N_QRY);
  transpose_lf<<<512, 256, 0, stream>>>(local_feat, lfT);
  knn_kernel<<<4096, 256, 0, stream>>>(pp, qp, knn);
  feat_kernel<<<2048, 256, 0, stream>>>(pp, qp, knn, lfT,
                                        w0, b0, g0, be0, m0, v0,
                                        w1, b1, g1, be1, m1, v1,
                                        w2, b2, out);
}

// Round 3
// 297.495 us; speedup vs baseline: 1.0881x; 1.0155x over previous
//
#include <hip/hip_runtime.h>
#include <cstdint>

#define M_PTS 8192
#define N_QRY 8192
#define BATCH 4

// ---------------- helpers ----------------
__device__ __forceinline__ float d2_exact(float qx, float qy, float qz, float q2, float4 p) {
#pragma clang fp contract(off)
  float dot = (qx * p.x + qy * p.y) + qz * p.z;   // reference op order, no fma
  return (q2 + p.w) - 2.0f * dot;
}

__device__ __forceinline__ unsigned flipf(float d) {
  unsigned u = __float_as_uint(d);
  return u ^ ((unsigned)((int)u >> 31) | 0x80000000u);   // order-preserving float->uint
}

__device__ __forceinline__ int lane_prefix(unsigned long long m) {
  return __builtin_amdgcn_mbcnt_hi((unsigned)(m >> 32),
         __builtin_amdgcn_mbcnt_lo((unsigned)m, 0));
}

__device__ __forceinline__ void ld_lds16(const float4* g, float4* l) {
  __builtin_amdgcn_global_load_lds((const __attribute__((address_space(1))) void*)g,
                                   (__attribute__((address_space(3))) void*)l, 16, 0, 0);
}

// Upper bound on the 16th-smallest of the 64 per-lane mins, via ballot bisection.
// Invariant: count(mn <= hi) >= 16 holds from init (hi = wave max -> 64). 10 steps
// give resolution (hi0-lo0)/1024; looseness only ADDS candidates, never drops one.
// Returned hi >= 16th-smallest lane-min >= 16th-smallest value of the scanned set.
__device__ __forceinline__ float tau16(float mn) {
  float lo = mn, hi = mn;
#pragma unroll
  for (int j = 1; j < 64; j <<= 1) {
    lo = fminf(lo, __shfl_xor(lo, j));
    hi = fmaxf(hi, __shfl_xor(hi, j));
  }
#pragma unroll
  for (int it = 0; it < 10; it++) {
    float mid = 0.5f * (lo + hi);
    int cnt = __popcll(__ballot(mn <= mid));
    if (cnt >= 16) hi = mid; else lo = mid;   // wave-uniform
  }
  return hi;
}

// ---------------- K0a: pack (x, y, z, x^2+y^2+z^2) ----------------
__global__ void pack_pts(const float* __restrict__ src, float4* __restrict__ dst, int total) {
#pragma clang fp contract(off)
  int i = blockIdx.x * 256 + threadIdx.x;
  if (i >= total) return;
  int b = i >> 13, m = i & (M_PTS - 1);
  const float* s = src + (size_t)b * 3 * M_PTS;
  float x = s[m], y = s[M_PTS + m], z = s[2 * M_PTS + m];
  float ss = (x * x + y * y) + z * z;   // matches jnp.sum(pts**2, axis=1) order
  dst[i] = make_float4(x, y, z, ss);
}

// ---------------- K0b: transpose local_feat (B,64,M) -> (B,M,64) ----------------
__global__ void transpose_lf(const float* __restrict__ lf, float* __restrict__ lfT) {
  __shared__ float tile[64][65];
  int bb = blockIdx.x >> 7;
  int m0 = (blockIdx.x & 127) << 6;
  int tm = threadIdx.x & 63;
  int tc = threadIdx.x >> 6;
  const float* src = lf + (size_t)bb * 64 * M_PTS;
#pragma unroll
  for (int i = 0; i < 16; i++) {
    int ch = i * 4 + tc;
    tile[ch][tm] = src[(size_t)ch * M_PTS + m0 + tm];
  }
  __syncthreads();
  float* dst = lfT + ((size_t)bb * M_PTS + m0) * 64;
#pragma unroll
  for (int i = 0; i < 16; i++) {
    int mm = i * 4 + tc;
    dst[(size_t)mm * 64 + tm] = tile[tm][mm];
  }
}

// ---------------- K1: exact KNN top-16, 2 queries per wave ----------------
// R2: monotone-tau fused structure. 8 chunks of 1024 points. tau is a running
// upper bound on the 16th-smallest distance over the PREFIX of chunks seen so
// far: any true global top-16 point p has d(p) <= global-16th <= prefix-16th
// <= tau, so chunks >= 1 collect in ONE fused pass (no stored e-array -> no
// compiler rematerialization). Chunk 0 does a min-pass + tau + collect-pass
// over just 1024 points, and guarantees >= 16 candidates. All candidates are
// re-scored with the exact reference d2 tree -> output bit-identical to R0/R1.
// LDS 22.5 KB -> 7 blocks/CU; live VGPRs ~45 -> __launch_bounds__(256,7).
__global__ void __launch_bounds__(256, 7) knn_kernel(const float4* __restrict__ pp,
                                                     const float4* __restrict__ qp,
                                                     int* __restrict__ knn_out) {
  __shared__ float4 spts[1024];          // 16 KB staged point chunk
  __shared__ unsigned cand[8][192];      // 6 KB candidate index buffers (per wave x 2 q)
  const int tid = threadIdx.x;
  const int lane = tid & 63;
  const int wave = tid >> 6;
  const int b = blockIdx.x >> 10;                 // 1024 blocks per batch
  const int qa = blockIdx.x * 8 + wave * 2;       // this wave's two queries
  const float4* pb = pp + ((size_t)b << 13);

  const float4 A4 = qp[qa];
  const float4 B4 = qp[qa + 1];
  const float axA = -2.0f * A4.x, ayA = -2.0f * A4.y, azA = -2.0f * A4.z;
  const float axB = -2.0f * B4.x, ayB = -2.0f * B4.y, azB = -2.0f * B4.z;

  int cntA = 0, cntB = 0;
  unsigned* cqA = cand[wave * 2 + 0];
  unsigned* cqB = cand[wave * 2 + 1];

  float mnA = 3.402823466e38f, mnB = 3.402823466e38f;
  float tauA = 0.0f, tauB = 0.0f;        // set after chunk-0 min pass

  auto collect = [&](float e, float tau, unsigned* cq, int& cnt, unsigned idx) {
    bool pred = e <= tau;
    unsigned long long mask = __ballot(pred);
    if (mask) {                           // wave-uniform; most j-iters skip here
      int pos = cnt + lane_prefix(mask);
      if (pred && pos < 192) cq[pos] = idx;
      cnt += __popcll(mask);
    }
  };

  for (int c = 0; c < 8; ++c) {
    __syncthreads();                      // protect spts from previous chunk's readers
#pragma unroll
    for (int i = 0; i < 4; i++) {
      const float4* g = pb + c * 1024 + i * 256 + wave * 64 + lane;
      ld_lds16(g, &spts[i * 256 + wave * 64]);   // wave-uniform LDS base + lane*16
    }
    __syncthreads();                      // drains vmcnt -> data visible

    if (c == 0) {
      // min-only pass over chunk 0 to seed tau (1024 pts, cheap)
#pragma unroll
      for (int j = 0; j < 16; j++) {
        float4 p = spts[j * 64 + lane];
        mnA = fminf(mnA, __builtin_fmaf(axA, p.x, __builtin_fmaf(ayA, p.y,
                         __builtin_fmaf(azA, p.z, p.w))));
        mnB = fminf(mnB, __builtin_fmaf(axB, p.x, __builtin_fmaf(ayB, p.y,
                         __builtin_fmaf(azB, p.z, p.w))));
      }
      tauA = tau16(mnA) + 0.01f;          // margin >> fma-vs-exact divergence
      tauB = tau16(mnB) + 0.01f;
    }

    // fused pass: compute e, collect with current (prefix) tau, update mins
#pragma unroll
    for (int j = 0; j < 16; j++) {
      float4 p = spts[j * 64 + lane];
      float ea = __builtin_fmaf(axA, p.x, __builtin_fmaf(ayA, p.y,
                 __builtin_fmaf(azA, p.z, p.w)));
      float eb = __builtin_fmaf(axB, p.x, __builtin_fmaf(ayB, p.y,
                 __builtin_fmaf(azB, p.z, p.w)));
      mnA = fminf(mnA, ea);
      mnB = fminf(mnB, eb);
      unsigned idx = (unsigned)(c * 1024 + j * 64 + lane);
      collect(ea, tauA, cqA, cntA, idx);
      collect(eb, tauB, cqB, cntB, idx);
    }

    if (c > 0 && c < 7) {                 // tighten tau for the next chunk
      tauA = fminf(tauA, tau16(mnA) + 0.01f);
      tauB = fminf(tauB, tau16(mnB) + 0.01f);
    }
  }

  auto finalize = [&](const unsigned* cq, int cnt, int gq,
                      float qx, float qy, float qz, float q2) {
    int E = cnt < 192 ? cnt : 192;            // E >= 16 guaranteed by chunk 0
    unsigned i0 = (lane < E) ? cq[lane] : 0u;
    unsigned i1 = (lane + 64 < E) ? cq[lane + 64] : 0u;
    unsigned i2 = (lane + 128 < E) ? cq[lane + 128] : 0u;
    float4 p0 = pb[i0];                       // parallel L2-hit loads
    float4 p1 = pb[i1];
    float4 p2 = pb[i2];
    unsigned long long k0 = ~0ull, k1 = ~0ull, k2 = ~0ull;
    if (lane < E)
      k0 = ((unsigned long long)flipf(d2_exact(qx, qy, qz, q2, p0)) << 32) | i0;
    if (lane + 64 < E)
      k1 = ((unsigned long long)flipf(d2_exact(qx, qy, qz, q2, p1)) << 32) | i1;
    if (lane + 128 < E)
      k2 = ((unsigned long long)flipf(d2_exact(qx, qy, qz, q2, p2)) << 32) | i2;
    unsigned my = 0;
#pragma unroll
    for (int t = 0; t < 16; t++) {
      unsigned long long m = k0 < k1 ? k0 : k1;
      if (k2 < m) m = k2;
#pragma unroll
      for (int j = 1; j < 64; j <<= 1) {
        unsigned long long o = __shfl_xor(m, j);
        if (o < m) m = o;
      }
      if (lane == t) my = (unsigned)m;
      if (k0 == m) k0 = ~0ull;
      else if (k1 == m) k1 = ~0ull;
      else if (k2 == m) k2 = ~0ull;
    }
    if (lane < 16) knn_out[(size_t)gq * 16 + lane] = (int)my;
  };

  finalize(cqA, cntA, qa,     A4.x, A4.y, A4.z, A4.w);
  finalize(cqB, cntB, qa + 1, B4.x, B4.y, B4.z, B4.w);
}

// ---------------- K2: fused feature pipeline, 16 queries per block ----------------
// lane = channel. w1 row lives in 64 VGPRs per lane (raw weights; BN scale applied
// after accumulation). R2: w1s pinned via empty asm ("+v") — R1 profile showed
// VGPR_Count=60 (< the 64 w1s values), i.e. the compiler rematerialized w1 loads
// inside the matvec loop. Pinning forces true register residency.
__global__ void __launch_bounds__(256, 4) feat_kernel(
    const float4* __restrict__ pp, const float4* __restrict__ qp,
    const int* __restrict__ knn, const float* __restrict__ lfT,
    const float* __restrict__ w0, const float* __restrict__ b0,
    const float* __restrict__ g0, const float* __restrict__ be0,
    const float* __restrict__ m0, const float* __restrict__ v0,
    const float* __restrict__ w1, const float* __restrict__ b1,
    const float* __restrict__ g1, const float* __restrict__ be1,
    const float* __restrict__ m1, const float* __restrict__ v1,
    const float* __restrict__ w2, const float* __restrict__ b2,
    float* __restrict__ out) {
  __shared__ float4 relbuf[4][16];
  __shared__ float4 f0v[4][64];
  __shared__ float outbuf[64][17];     // +1 pad breaks write-phase bank conflicts
  const int tid = threadIdx.x;
  const int lane = tid & 63;
  const int wave = tid >> 6;
  const int gq0 = blockIdx.x * 16;
  const int b = gq0 >> 13;

  // BN folds (inline; fp order matches R0's fold_kernel)
  const float inv0 = g0[lane] / sqrtf(v0[lane] + 1e-5f);
  const float w00 = w0[lane * 3 + 0] * inv0;
  const float w01 = w0[lane * 3 + 1] * inv0;
  const float w02 = w0[lane * 3 + 2] * inv0;
  const float bb0 = (b0[lane] - m0[lane]) * inv0 + be0[lane];
  const float inv1 = g1[lane] / sqrtf(v1[lane] + 1e-5f);
  const float bb1 = (b1[lane] - m1[lane]) * inv1 + be1[lane];

  float w1s[64];
#pragma unroll
  for (int i = 0; i < 16; i++) {
    float4 t = ((const float4*)(w1 + (size_t)lane * 64))[i];
    w1s[i * 4 + 0] = t.x; w1s[i * 4 + 1] = t.y;
    w1s[i * 4 + 2] = t.z; w1s[i * 4 + 3] = t.w;
  }
  // Pin each w1 value into a VGPR: compiler can no longer rematerialize the
  // global load inside the matvec loop (it must assume the asm changed them).
#pragma unroll
  for (int k = 0; k < 64; k++) asm volatile("" : "+v"(w1s[k]));

  const float w2a = w2[lane], w2b = w2[64 + lane];
  const float bias2 = b2[0];
  const float4* pb = pp + ((size_t)b << 13);
  const float* lfb = lfT + (((size_t)b << 13)) * 64;

  for (int qi = 0; qi < 4; qi++) {
    const int gq = gq0 + wave * 4 + qi;
    const float4 q4 = qp[gq];
    int nk = knn[(size_t)gq * 16 + (lane & 15)];
    float4 pk = pb[nk];
    if (lane < 16)
      relbuf[wave][lane] = make_float4(pk.x - q4.x, pk.y - q4.y, pk.z - q4.z, 0.0f);
    // wave-local RAW: lgkmcnt ordering suffices, no barrier

    float g = 0.0f, f0 = 0, f1 = 0, f2 = 0, f3 = 0;
#pragma unroll
    for (int k = 0; k < 16; k++) {
      float4 r = relbuf[wave][k];
      float y = fmaxf(0.0f, w00 * r.x + w01 * r.y + w02 * r.z + bb0);
      g = fmaxf(g, y);
      if (k == 0) f0 = y; else if (k == 1) f1 = y;
      else if (k == 2) f2 = y; else if (k == 3) f3 = y;
    }
    f0v[wave][lane] = make_float4(f0, f1, f2, f3);

    float a0 = 0, a1 = 0, a2 = 0, a3 = 0;
#pragma unroll
    for (int c2 = 0; c2 < 64; c2++) {
      float w = w1s[c2];                 // register (pinned, compile-time index)
      float4 fb = f0v[wave][c2];         // LDS broadcast
      a0 = fmaf(w, fb.x, a0); a1 = fmaf(w, fb.y, a1);
      a2 = fmaf(w, fb.z, a2); a3 = fmaf(w, fb.w, a3);
    }
    float r0 = fmaxf(0.0f, fmaf(a0, inv1, bb1));
    float r1 = fmaxf(0.0f, fmaf(a1, inv1, bb1));
    float r2 = fmaxf(0.0f, fmaf(a2, inv1, bb1));
    float r3 = fmaxf(0.0f, fmaf(a3, inv1, bb1));

    int i0 = __shfl(nk, 0), i1 = __shfl(nk, 1), i2 = __shfl(nk, 2), i3 = __shfl(nk, 3);
    float p0 = lfb[(size_t)i0 * 64 + lane];
    float p1 = lfb[(size_t)i1 * 64 + lane];
    float p2 = lfb[(size_t)i2 * 64 + lane];
    float p3 = lfb[(size_t)i3 * 64 + lane];

    float s0 = w2a * r0, s1 = w2a * r1, s2 = w2a * r2, s3 = w2a * r3, tg = w2b * g;
#pragma unroll
    for (int j = 1; j < 64; j <<= 1) {
      s0 += __shfl_xor(s0, j);
      s1 += __shfl_xor(s1, j);
      s2 += __shfl_xor(s2, j);
      s3 += __shfl_xor(s3, j);
      tg += __shfl_xor(tg, j);
    }
    float wk0 = 1.0f / (1.0f + __expf(-(s0 + tg + bias2)));
    float wk1 = 1.0f / (1.0f + __expf(-(s1 + tg + bias2)));
    float wk2 = 1.0f / (1.0f + __expf(-(s2 + tg + bias2)));
    float wk3 = 1.0f / (1.0f + __expf(-(s3 + tg + bias2)));

    float oc = ((1.0f - wk0) * r0 + wk0 * p0)
             + ((1.0f - wk1) * r1 + wk1 * p1)
             + ((1.0f - wk2) * r2 + wk2 * p2)
             + ((1.0f - wk3) * r3 + wk3 * p3);
    outbuf[lane][wave * 4 + qi] = oc;
  }
  __syncthreads();

  // coalesced output: thread t -> channel c = t>>2, 4 queries via float4
  int c = tid >> 2, j = tid & 3;
  float4 o4 = make_float4(outbuf[c][j * 4 + 0], outbuf[c][j * 4 + 1],
                          outbuf[c][j * 4 + 2], outbuf[c][j * 4 + 3]);
  *(float4*)(out + (((size_t)(b * 64 + c)) << 13) + (gq0 & (N_QRY - 1)) + j * 4) = o4;
}

extern "C" void kernel_launch(void* const* d_in, const int* in_sizes, int n_in,
                              void* d_out, int out_size, void* d_ws, size_t ws_size,
                              hipStream_t stream) {
  (void)in_sizes; (void)n_in; (void)out_size; (void)ws_size;
  const float* original_pts = (const float*)d_in[0];
  const float* query_pts   = (const float*)d_in[1];
  const float* local_feat  = (const float*)d_in[2];
  const float* w0 = (const float*)d_in[3];
  const float* b0 = (const float*)d_in[4];
  const float* g0 = (const float*)d_in[5];
  const float* be0 = (const float*)d_in[6];
  const float* m0 = (const float*)d_in[7];
  const float* v0 = (const float*)d_in[8];
  const float* w1 = (const float*)d_in[9];
  const float* b1 = (const float*)d_in[10];
  const float* g1 = (const float*)d_in[11];
  const float* be1 = (const float*)d_in[12];
  const float* m1 = (const float*)d_in[13];
  const float* v1 = (const float*)d_in[14];
  const float* w2 = (const float*)d_in[15];
  const float* b2 = (const float*)d_in[16];
  float* out = (float*)d_out;

  // workspace layout (16B aligned), total ~11.5 MB
  char* ws = (char*)d_ws;
  float4* pp  = (float4*)(ws);                 // 512 KB
  float4* qp  = (float4*)(ws + 524288);        // 512 KB
  float*  lfT = (float*)(ws + 1048576);        // 8 MB
  int*    knn = (int*)(ws + 9437184);          // 2 MB

  pack_pts<<<128, 256, 0, stream>>>(original_pts, pp, BATCH * M_PTS);
  pack_pts<<<128, 256, 0, stream>>>(query_pts, qp, BATCH * N_QRY);
  transpose_lf<<<512, 256, 0, stream>>>(local_feat, lfT);
  knn_kernel<<<4096, 256, 0, stream>>>(pp, qp, knn);
  feat_kernel<<<2048, 256, 0, stream>>>(pp, qp, knn, lfT,
                                        w0, b0, g0, be0, m0, v0,
                                        w1, b1, g1, be1, m1, v1,
                                        w2, b2, out);
}

// Round 4
// 257.830 us; speedup vs baseline: 1.2555x; 1.1538x over previous
//
#include <hip/hip_runtime.h>
#include <cstdint>

#define M_PTS 8192
#define N_QRY 8192
#define BATCH 4

typedef unsigned long long ull;

// ---------------- helpers ----------------
__device__ __forceinline__ float d2_exact(float qx, float qy, float qz, float q2, float4 p) {
#pragma clang fp contract(off)
  float dot = (qx * p.x + qy * p.y) + qz * p.z;   // reference op order, no fma
  return (q2 + p.w) - 2.0f * dot;
}

__device__ __forceinline__ unsigned flipf(float d) {
  unsigned u = __float_as_uint(d);
  return u ^ ((unsigned)((int)u >> 31) | 0x80000000u);   // order-preserving float->uint
}

__device__ __forceinline__ int lane_prefix(unsigned long long m) {
  return __builtin_amdgcn_mbcnt_hi((unsigned)(m >> 32),
         __builtin_amdgcn_mbcnt_lo((unsigned)m, 0));
}

__device__ __forceinline__ void ld_lds16(const float4* g, float4* l) {
  __builtin_amdgcn_global_load_lds((const __attribute__((address_space(1))) void*)g,
                                   (__attribute__((address_space(3))) void*)l, 16, 0, 0);
}

// Upper bound on the 16th-smallest of the 64 per-lane mins, via ballot bisection.
// Invariant: count(mn <= hi) >= 16 holds from init (hi = wave max -> 64). 10 steps
// give resolution (hi0-lo0)/1024; looseness only ADDS candidates, never drops one.
__device__ __forceinline__ float tau16(float mn) {
  float lo = mn, hi = mn;
#pragma unroll
  for (int j = 1; j < 64; j <<= 1) {
    lo = fminf(lo, __shfl_xor(lo, j));
    hi = fmaxf(hi, __shfl_xor(hi, j));
  }
#pragma unroll
  for (int it = 0; it < 10; it++) {
    float mid = 0.5f * (lo + hi);
    int cnt = __popcll(__ballot(mn <= mid));
    if (cnt >= 16) hi = mid; else lo = mid;   // wave-uniform
  }
  return hi;
}

// Full 64-lane ascending bitonic sort of u64 keys; lane i ends with the i-th
// smallest. Same network/orientation as the R0-verified rank16 (which read
// lane 15 as the 16th smallest), lifted to u64.
__device__ __forceinline__ ull bsort64(ull v, int lane) {
#pragma unroll
  for (int k = 2; k <= 64; k <<= 1) {
#pragma unroll
    for (int j = k >> 1; j >= 1; j >>= 1) {
      ull o = __shfl_xor(v, j);
      bool keepmin = (((lane & k) == 0) == ((lane & j) == 0));
      ull lo = v < o ? v : o;
      ull hi = v < o ? o : v;
      v = keepmin ? lo : hi;
    }
  }
  return v;
}

// ---------------- K0a: pack (x, y, z, x^2+y^2+z^2) ----------------
__global__ void pack_pts(const float* __restrict__ src, float4* __restrict__ dst, int total) {
#pragma clang fp contract(off)
  int i = blockIdx.x * 256 + threadIdx.x;
  if (i >= total) return;
  int b = i >> 13, m = i & (M_PTS - 1);
  const float* s = src + (size_t)b * 3 * M_PTS;
  float x = s[m], y = s[M_PTS + m], z = s[2 * M_PTS + m];
  float ss = (x * x + y * y) + z * z;   // matches jnp.sum(pts**2, axis=1) order
  dst[i] = make_float4(x, y, z, ss);
}

// ---------------- K0b: transpose local_feat (B,64,M) -> (B,M,64) ----------------
__global__ void transpose_lf(const float* __restrict__ lf, float* __restrict__ lfT) {
  __shared__ float tile[64][65];
  int bb = blockIdx.x >> 7;
  int m0 = (blockIdx.x & 127) << 6;
  int tm = threadIdx.x & 63;
  int tc = threadIdx.x >> 6;
  const float* src = lf + (size_t)bb * 64 * M_PTS;
#pragma unroll
  for (int i = 0; i < 16; i++) {
    int ch = i * 4 + tc;
    tile[ch][tm] = src[(size_t)ch * M_PTS + m0 + tm];
  }
  __syncthreads();
  float* dst = lfT + ((size_t)bb * M_PTS + m0) * 64;
#pragma unroll
  for (int i = 0; i < 16; i++) {
    int mm = i * 4 + tc;
    dst[(size_t)mm * 64 + tm] = tile[tm][mm];
  }
}

// ---------------- K1: exact KNN top-16, 2 queries per wave ----------------
// R4: (a) double-buffered 512-pt sub-chunk staging — next sub-chunk's
// global_load_lds issued BEFORE computing the current one, so the single
// per-iteration barrier's vmcnt(0) drain is covered by compute (R3 had 8 full
// load-stall barriers); (b) monotone prefix tau (seeded on first 1024 pts,
// tightened at 2048/4096/6144 prefixes — stale tau is only looser, never drops
// a true neighbor); (c) O(1)-sort finalize: lane-min -> 64-lane bitonic sort
// -> T = 16th-smallest lane-min (upper bound on true 16th key; survivors <= 48,
// in exactly the 16 lanes whose min <= T) -> ballot-compact -> second bitonic
// sort -> lanes 0..15 emit. Same exact-rescore u64 (dist,idx) keys as R0-R3
// -> output bit-identical.
__global__ void __launch_bounds__(256, 7) knn_kernel(const float4* __restrict__ pp,
                                                     const float4* __restrict__ qp,
                                                     int* __restrict__ knn_out) {
  __shared__ float4 spts[2][512];        // 16 KB double-buffered point stage
  __shared__ ull cbuf[8][96];            // 6 KB cand buffers (per wave x 2 q; 192 u32 view)
  const int tid = threadIdx.x;
  const int lane = tid & 63;
  const int wave = tid >> 6;
  const int b = blockIdx.x >> 10;                 // 1024 blocks per batch
  const int qa = blockIdx.x * 8 + wave * 2;       // this wave's two queries
  const float4* pb = pp + ((size_t)b << 13);

  const float4 A4 = qp[qa];
  const float4 B4 = qp[qa + 1];
  const float axA = -2.0f * A4.x, ayA = -2.0f * A4.y, azA = -2.0f * A4.z;
  const float axB = -2.0f * B4.x, ayB = -2.0f * B4.y, azB = -2.0f * B4.z;

  int cntA = 0, cntB = 0;
  unsigned* cqA = (unsigned*)cbuf[wave * 2 + 0];
  unsigned* cqB = (unsigned*)cbuf[wave * 2 + 1];

  float mnA = 3.402823466e38f, mnB = 3.402823466e38f;
  float tauA = 0.0f, tauB = 0.0f;

  auto stage = [&](float4* dst, int s) {
#pragma unroll
    for (int i = 0; i < 2; i++) {
      const float4* g = pb + s * 512 + i * 256 + wave * 64 + lane;
      ld_lds16(g, &dst[i * 256 + wave * 64]);   // wave-uniform LDS base + lane*16
    }
  };

  auto minpass = [&](const float4* sp) {
#pragma unroll
    for (int j = 0; j < 8; j++) {
      float4 p = sp[j * 64 + lane];
      mnA = fminf(mnA, __builtin_fmaf(axA, p.x, __builtin_fmaf(ayA, p.y,
                       __builtin_fmaf(azA, p.z, p.w))));
      mnB = fminf(mnB, __builtin_fmaf(axB, p.x, __builtin_fmaf(ayB, p.y,
                       __builtin_fmaf(azB, p.z, p.w))));
    }
  };

  auto collect = [&](float e, float tau, unsigned* cq, int& cnt, unsigned idx) {
    bool pred = e <= tau;
    unsigned long long mask = __ballot(pred);
    if (mask) {                           // wave-uniform; most iters skip here
      int pos = cnt + lane_prefix(mask);
      if (pred && pos < 192) cq[pos] = idx;
      cnt += __popcll(mask);
    }
  };

  auto fused = [&](const float4* sp, unsigned base) {
#pragma unroll
    for (int j = 0; j < 8; j++) {
      float4 p = sp[j * 64 + lane];
      float ea = __builtin_fmaf(axA, p.x, __builtin_fmaf(ayA, p.y,
                 __builtin_fmaf(azA, p.z, p.w)));
      float eb = __builtin_fmaf(axB, p.x, __builtin_fmaf(ayB, p.y,
                 __builtin_fmaf(azB, p.z, p.w)));
      mnA = fminf(mnA, ea);
      mnB = fminf(mnB, eb);
      unsigned idx = base + j * 64 + lane;
      collect(ea, tauA, cqA, cntA, idx);
      collect(eb, tauB, cqB, cntB, idx);
    }
  };

  // ---- prologue: seed tau on first 1024 pts (two-pass over sc0/sc1) ----
  stage(spts[0], 0);
  __syncthreads();                       // sc0 visible
  stage(spts[1], 1);                     // in flight during minpass(sc0)
  minpass(spts[0]);
  __syncthreads();                       // sc1 visible
  minpass(spts[1]);
  tauA = tau16(mnA) + 0.01f;             // margin >> fma-vs-exact divergence
  tauB = tau16(mnB) + 0.01f;
  fused(spts[0], 0);
  fused(spts[1], 512);
  __syncthreads();                       // all waves done reading sc0/sc1
  stage(spts[0], 2);
  __syncthreads();                       // sc2 visible (single true stall)

  // ---- steady state: stage next sub-chunk, compute current, barrier ----
  for (int s = 2; s < 16; ++s) {
    if (s < 15) stage(spts[(s + 1) & 1], s + 1);
    fused(spts[s & 1], (unsigned)(s * 512));
    if (s == 3 || s == 7 || s == 11) {   // tighten tau at 2048/4096/6144 prefixes
      tauA = fminf(tauA, tau16(mnA) + 0.01f);
      tauB = fminf(tauB, tau16(mnB) + 0.01f);
    }
    __syncthreads();                     // drains vmcnt -> next buffer visible;
  }                                      // also protects the swap

  auto finalize = [&](ull* cb, int cnt, int gq,
                      float qx, float qy, float qz, float q2) {
    unsigned* cq = (unsigned*)cb;
    int E = cnt < 192 ? cnt : 192;            // E >= 16 guaranteed by prologue tau
    unsigned i0 = (lane < E) ? cq[lane] : 0u;
    unsigned i1 = (lane + 64 < E) ? cq[lane + 64] : 0u;
    unsigned i2 = (lane + 128 < E) ? cq[lane + 128] : 0u;
    float4 p0 = pb[i0];                       // parallel L2-hit loads
    float4 p1 = pb[i1];
    float4 p2 = pb[i2];
    ull k0 = ~0ull, k1 = ~0ull, k2 = ~0ull;
    if (lane < E)
      k0 = ((ull)flipf(d2_exact(qx, qy, qz, q2, p0)) << 32) | i0;
    if (lane + 64 < E)
      k1 = ((ull)flipf(d2_exact(qx, qy, qz, q2, p1)) << 32) | i1;
    if (lane + 128 < E)
      k2 = ((ull)flipf(d2_exact(qx, qy, qz, q2, p2)) << 32) | i2;
    // lane-min, then T = 16th-smallest lane-min (valid: E>=16 -> lanes 0..15
    // all hold a real k0). Every true top-16 key <= T; keys <= T live only in
    // the 16 lanes whose lane-min <= T -> at most 48 survivors.
    ull ml = k0 < k1 ? k0 : k1;
    if (k2 < ml) ml = k2;
    ull T = __shfl(bsort64(ml, lane), 15);
    // ballot-compact survivors into cb (u64 view; cq reads already consumed)
    int c2 = 0;
    {
      bool pr = k0 <= T; ull m = __ballot(pr);
      int pos = c2 + lane_prefix(m);
      if (pr) cb[pos] = k0;
      c2 += __popcll(m);
    }
    {
      bool pr = k1 <= T; ull m = __ballot(pr);
      int pos = c2 + lane_prefix(m);
      if (pr) cb[pos] = k1;
      c2 += __popcll(m);
    }
    {
      bool pr = k2 <= T; ull m = __ballot(pr);
      int pos = c2 + lane_prefix(m);
      if (pr) cb[pos] = k2;
      c2 += __popcll(m);
    }
    // wave-local RAW: lgkmcnt ordering suffices, no barrier
    ull kk = (lane < c2) ? cb[lane] : ~0ull;
    ull fin = bsort64(kk, lane);
    if (lane < 16) knn_out[(size_t)gq * 16 + lane] = (int)(unsigned)fin;
  };

  finalize(cbuf[wave * 2 + 0], cntA, qa,     A4.x, A4.y, A4.z, A4.w);
  finalize(cbuf[wave * 2 + 1], cntB, qa + 1, B4.x, B4.y, B4.z, B4.w);
}

// ---------------- K2: fused feature pipeline, 16 queries per block ----------------
// lane = channel. w1 row lives in 64 VGPRs per lane (raw weights; BN scale applied
// after accumulation). w1s pinned via empty asm ("+v") so the compiler cannot
// rematerialize the global loads inside the matvec loop.
__global__ void __launch_bounds__(256, 4) feat_kernel(
    const float4* __restrict__ pp, const float4* __restrict__ qp,
    const int* __restrict__ knn, const float* __restrict__ lfT,
    const float* __restrict__ w0, const float* __restrict__ b0,
    const float* __restrict__ g0, const float* __restrict__ be0,
    const float* __restrict__ m0, const float* __restrict__ v0,
    const float* __restrict__ w1, const float* __restrict__ b1,
    const float* __restrict__ g1, const float* __restrict__ be1,
    const float* __restrict__ m1, const float* __restrict__ v1,
    const float* __restrict__ w2, const float* __restrict__ b2,
    float* __restrict__ out) {
  __shared__ float4 relbuf[4][16];
  __shared__ float4 f0v[4][64];
  __shared__ float outbuf[64][17];     // +1 pad breaks write-phase bank conflicts
  const int tid = threadIdx.x;
  const int lane = tid & 63;
  const int wave = tid >> 6;
  const int gq0 = blockIdx.x * 16;
  const int b = gq0 >> 13;

  // BN folds (inline; fp order matches R0's fold_kernel)
  const float inv0 = g0[lane] / sqrtf(v0[lane] + 1e-5f);
  const float w00 = w0[lane * 3 + 0] * inv0;
  const float w01 = w0[lane * 3 + 1] * inv0;
  const float w02 = w0[lane * 3 + 2] * inv0;
  const float bb0 = (b0[lane] - m0[lane]) * inv0 + be0[lane];
  const float inv1 = g1[lane] / sqrtf(v1[lane] + 1e-5f);
  const float bb1 = (b1[lane] - m1[lane]) * inv1 + be1[lane];

  float w1s[64];
#pragma unroll
  for (int i = 0; i < 16; i++) {
    float4 t = ((const float4*)(w1 + (size_t)lane * 64))[i];
    w1s[i * 4 + 0] = t.x; w1s[i * 4 + 1] = t.y;
    w1s[i * 4 + 2] = t.z; w1s[i * 4 + 3] = t.w;
  }
  // Pin each w1 value into a VGPR: compiler can no longer rematerialize the
  // global load inside the matvec loop.
#pragma unroll
  for (int k = 0; k < 64; k++) asm volatile("" : "+v"(w1s[k]));

  const float w2a = w2[lane], w2b = w2[64 + lane];
  const float bias2 = b2[0];
  const float4* pb = pp + ((size_t)b << 13);
  const float* lfb = lfT + (((size_t)b << 13)) * 64;

  for (int qi = 0; qi < 4; qi++) {
    const int gq = gq0 + wave * 4 + qi;
    const float4 q4 = qp[gq];
    int nk = knn[(size_t)gq * 16 + (lane & 15)];
    float4 pk = pb[nk];
    if (lane < 16)
      relbuf[wave][lane] = make_float4(pk.x - q4.x, pk.y - q4.y, pk.z - q4.z, 0.0f);
    // wave-local RAW: lgkmcnt ordering suffices, no barrier

    float g = 0.0f, f0 = 0, f1 = 0, f2 = 0, f3 = 0;
#pragma unroll
    for (int k = 0; k < 16; k++) {
      float4 r = relbuf[wave][k];
      float y = fmaxf(0.0f, w00 * r.x + w01 * r.y + w02 * r.z + bb0);
      g = fmaxf(g, y);
      if (k == 0) f0 = y; else if (k == 1) f1 = y;
      else if (k == 2) f2 = y; else if (k == 3) f3 = y;
    }
    f0v[wave][lane] = make_float4(f0, f1, f2, f3);

    float a0 = 0, a1 = 0, a2 = 0, a3 = 0;
#pragma unroll
    for (int c2 = 0; c2 < 64; c2++) {
      float w = w1s[c2];                 // register (pinned, compile-time index)
      float4 fb = f0v[wave][c2];         // LDS broadcast
      a0 = fmaf(w, fb.x, a0); a1 = fmaf(w, fb.y, a1);
      a2 = fmaf(w, fb.z, a2); a3 = fmaf(w, fb.w, a3);
    }
    float r0 = fmaxf(0.0f, fmaf(a0, inv1, bb1));
    float r1 = fmaxf(0.0f, fmaf(a1, inv1, bb1));
    float r2 = fmaxf(0.0f, fmaf(a2, inv1, bb1));
    float r3 = fmaxf(0.0f, fmaf(a3, inv1, bb1));

    int i0 = __shfl(nk, 0), i1 = __shfl(nk, 1), i2 = __shfl(nk, 2), i3 = __shfl(nk, 3);
    float p0 = lfb[(size_t)i0 * 64 + lane];
    float p1 = lfb[(size_t)i1 * 64 + lane];
    float p2 = lfb[(size_t)i2 * 64 + lane];
    float p3 = lfb[(size_t)i3 * 64 + lane];

    float s0 = w2a * r0, s1 = w2a * r1, s2 = w2a * r2, s3 = w2a * r3, tg = w2b * g;
#pragma unroll
    for (int j = 1; j < 64; j <<= 1) {
      s0 += __shfl_xor(s0, j);
      s1 += __shfl_xor(s1, j);
      s2 += __shfl_xor(s2, j);
      s3 += __shfl_xor(s3, j);
      tg += __shfl_xor(tg, j);
    }
    float wk0 = 1.0f / (1.0f + __expf(-(s0 + tg + bias2)));
    float wk1 = 1.0f / (1.0f + __expf(-(s1 + tg + bias2)));
    float wk2 = 1.0f / (1.0f + __expf(-(s2 + tg + bias2)));
    float wk3 = 1.0f / (1.0f + __expf(-(s3 + tg + bias2)));

    float oc = ((1.0f - wk0) * r0 + wk0 * p0)
             + ((1.0f - wk1) * r1 + wk1 * p1)
             + ((1.0f - wk2) * r2 + wk2 * p2)
             + ((1.0f - wk3) * r3 + wk3 * p3);
    outbuf[lane][wave * 4 + qi] = oc;
  }
  __syncthreads();

  // coalesced output: thread t -> channel c = t>>2, 4 queries via float4
  int c = tid >> 2, j = tid & 3;
  float4 o4 = make_float4(outbuf[c][j * 4 + 0], outbuf[c][j * 4 + 1],
                          outbuf[c][j * 4 + 2], outbuf[c][j * 4 + 3]);
  *(float4*)(out + (((size_t)(b * 64 + c)) << 13) + (gq0 & (N_QRY - 1)) + j * 4) = o4;
}

extern "C" void kernel_launch(void* const* d_in, const int* in_sizes, int n_in,
                              void* d_out, int out_size, void* d_ws, size_t ws_size,
                              hipStream_t stream) {
  (void)in_sizes; (void)n_in; (void)out_size; (void)ws_size;
  const float* original_pts = (const float*)d_in[0];
  const float* query_pts   = (const float*)d_in[1];
  const float* local_feat  = (const float*)d_in[2];
  const float* w0 = (const float*)d_in[3];
  const float* b0 = (const float*)d_in[4];
  const float* g0 = (const float*)d_in[5];
  const float* be0 = (const float*)d_in[6];
  const float* m0 = (const float*)d_in[7];
  const float* v0 = (const float*)d_in[8];
  const float* w1 = (const float*)d_in[9];
  const float* b1 = (const float*)d_in[10];
  const float* g1 = (const float*)d_in[11];
  const float* be1 = (const float*)d_in[12];
  const float* m1 = (const float*)d_in[13];
  const float* v1 = (const float*)d_in[14];
  const float* w2 = (const float*)d_in[15];
  const float* b2 = (const float*)d_in[16];
  float* out = (float*)d_out;

  // workspace layout (16B aligned), total ~11.5 MB
  char* ws = (char*)d_ws;
  float4* pp  = (float4*)(ws);                 // 512 KB
  float4* qp  = (float4*)(ws + 524288);        // 512 KB
  float*  lfT = (float*)(ws + 1048576);        // 8 MB
  int*    knn = (int*)(ws + 9437184);          // 2 MB

  pack_pts<<<128, 256, 0, stream>>>(original_pts, pp, BATCH * M_PTS);
  pack_pts<<<128, 256, 0, stream>>>(query_pts, qp, BATCH * N_QRY);
  transpose_lf<<<512, 256, 0, stream>>>(local_feat, lfT);
  knn_kernel<<<4096, 256, 0, stream>>>(pp, qp, knn);
  feat_kernel<<<2048, 256, 0, stream>>>(pp, qp, knn, lfT,
                                        w0, b0, g0, be0, m0, v0,
                                        w1, b1, g1, be1, m1, v1,
                                        w2, b2, out);
}